// Round 1
// baseline (488.805 us; speedup 1.0000x reference)
//
#include <hip/hip_runtime.h>
#include <float.h>

#define N_TOKENS 65536
#define N_EMB    1024
#define DIM      256

// ---------------- kernel 1: codebook row squared-norms ----------------
// one wave (64 lanes) per codebook row; float4 per lane (64*4 = 256 elems)
__global__ __launch_bounds__(256) void cnorm_kernel(const float* __restrict__ cb,
                                                    float* __restrict__ cn2) {
    int gwave = (blockIdx.x * 256 + threadIdx.x) >> 6;
    int lane  = threadIdx.x & 63;
    if (gwave >= N_EMB) return;
    float4 v = ((const float4*)cb)[gwave * 64 + lane];
    float s = v.x * v.x + v.y * v.y + v.z * v.z + v.w * v.w;
#pragma unroll
    for (int m = 1; m < 64; m <<= 1) s += __shfl_xor(s, m);
    if (lane == 0) cn2[gwave] = s;
}

// ---------------- kernel 2: argmin over squared distances ----------------
// dist[n][k] = (||x_n||^2 + ||c_k||^2) - 2 * (x_n . c_k), faithful fp32.
// BM=128 tokens x BN=128 codes per tile, K-loop over D in BK=32 chunks.
// 256 threads, each owns an 8x8 micro-tile (r = token group, c = code group).
constexpr int BM = 128, BN = 128, BK = 32;
constexpr int LDT = BM + 4;  // padded LDS row

__global__ __launch_bounds__(256) void argmin_kernel(
        const float* __restrict__ z, const float* __restrict__ cb,
        const float* __restrict__ cn2, int* __restrict__ out_idx) {
    __shared__ float As[BK * LDT];
    __shared__ float Bs[BK * LDT];
    const int tid = threadIdx.x;
    const int m0  = blockIdx.x * BM;
    const int r   = tid >> 4;   // 0..15 token group (8 tokens each)
    const int c   = tid & 15;   // 0..15 code group  (8 codes each)
    const int qq  = tid & 7;    // staging: float4 column within BK
    const int mr  = tid >> 3;   // staging: row 0..31

    float xn[8];
    float bestD[8];
    int   bestI[8];
#pragma unroll
    for (int i = 0; i < 8; ++i) { xn[i] = 0.f; bestD[i] = FLT_MAX; bestI[i] = 0x7fffffff; }

    for (int n0 = 0; n0 < N_EMB; n0 += BN) {
        float acc[8][8];
#pragma unroll
        for (int i = 0; i < 8; ++i)
#pragma unroll
            for (int j = 0; j < 8; ++j) acc[i][j] = 0.f;

        for (int d0 = 0; d0 < DIM; d0 += BK) {
            // ---- stage A (tokens) and B (codes) tiles, transposed to [k][m] ----
#pragma unroll
            for (int s = 0; s < 4; ++s) {
                int m = mr + 32 * s;
                float4 av = *(const float4*)(z  + (size_t)(m0 + m) * DIM + d0 + qq * 4);
                float4 bv = *(const float4*)(cb + (size_t)(n0 + m) * DIM + d0 + qq * 4);
                As[(qq * 4 + 0) * LDT + m] = av.x;
                As[(qq * 4 + 1) * LDT + m] = av.y;
                As[(qq * 4 + 2) * LDT + m] = av.z;
                As[(qq * 4 + 3) * LDT + m] = av.w;
                Bs[(qq * 4 + 0) * LDT + m] = bv.x;
                Bs[(qq * 4 + 1) * LDT + m] = bv.y;
                Bs[(qq * 4 + 2) * LDT + m] = bv.z;
                Bs[(qq * 4 + 3) * LDT + m] = bv.w;
            }
            __syncthreads();
            const bool first = (n0 == 0);
#pragma unroll 8
            for (int kk = 0; kk < BK; ++kk) {
                float a[8], b[8];
                *(float4*)&a[0] = *(const float4*)&As[kk * LDT + r * 8];
                *(float4*)&a[4] = *(const float4*)&As[kk * LDT + r * 8 + 4];
                *(float4*)&b[0] = *(const float4*)&Bs[kk * LDT + c * 8];
                *(float4*)&b[4] = *(const float4*)&Bs[kk * LDT + c * 8 + 4];
                if (first) {
#pragma unroll
                    for (int i = 0; i < 8; ++i) xn[i] += a[i] * a[i];
                }
#pragma unroll
                for (int i = 0; i < 8; ++i)
#pragma unroll
                    for (int j = 0; j < 8; ++j)
                        acc[i][j] += a[i] * b[j];
            }
            __syncthreads();
        }

        // ---- per-tile argmin update ----
        float cn[8];
#pragma unroll
        for (int j = 0; j < 8; ++j) cn[j] = cn2[n0 + c * 8 + j];
        {
#pragma clang fp contract(off)
#pragma unroll
            for (int i = 0; i < 8; ++i) {
                float bd = FLT_MAX; int bi = 0x7fffffff;
#pragma unroll
                for (int j = 0; j < 8; ++j) {
                    float t1 = xn[i] + cn[j];       // ||x||^2 + ||c||^2  (rounded)
                    float t2 = 2.0f * acc[i][j];    // 2 * dot            (rounded)
                    float dist = t1 - t2;
                    if (dist < bd) { bd = dist; bi = n0 + c * 8 + j; }
                }
                // butterfly across the 16 code-group lanes (contiguous in wave)
#pragma unroll
                for (int mask = 1; mask <= 8; mask <<= 1) {
                    float od = __shfl_xor(bd, mask);
                    int   oi = __shfl_xor(bi, mask);
                    if (od < bd || (od == bd && oi < bi)) { bd = od; bi = oi; }
                }
                if (bd < bestD[i]) { bestD[i] = bd; bestI[i] = bi; }  // earlier n0 wins ties
            }
        }
    }
    if (c == 0) {
#pragma unroll
        for (int i = 0; i < 8; ++i) out_idx[m0 + r * 8 + i] = bestI[i];
    }
}

// ---------------- kernel 3: gather + straight-through out + loss partials ----------------
// each block: 1024 float4 (16 tokens); each wave covers exactly one token row per step
__global__ __launch_bounds__(256) void gather_kernel(
        const float* __restrict__ z, const float* __restrict__ cb,
        const int* __restrict__ idx, float* __restrict__ out,
        float* __restrict__ partials) {
    const int tid = threadIdx.x;
    const int f0  = blockIdx.x * 1024;
    float lsum = 0.f;
#pragma unroll
    for (int s = 0; s < 4; ++s) {
        int f     = f0 + s * 256 + tid;
        int token = f >> 6;
        int col   = f & 63;
        int k     = idx[token];
        float4 zv = ((const float4*)z)[f];
        float4 qv = ((const float4*)cb)[k * 64 + col];
        float4 ov;
        ov.x = zv.x + (qv.x - zv.x);   // faithful straight-through rounding
        ov.y = zv.y + (qv.y - zv.y);
        ov.z = zv.z + (qv.z - zv.z);
        ov.w = zv.w + (qv.w - zv.w);
        ((float4*)out)[f] = ov;
        float ex = zv.x - qv.x, ey = zv.y - qv.y, ez = zv.z - qv.z, ew = zv.w - qv.w;
        lsum += ex * ex + ey * ey + ez * ez + ew * ew;
    }
#pragma unroll
    for (int m = 1; m < 64; m <<= 1) lsum += __shfl_xor(lsum, m);
    __shared__ float wsum[4];
    if ((tid & 63) == 0) wsum[tid >> 6] = lsum;
    __syncthreads();
    if (tid == 0) partials[blockIdx.x] = (wsum[0] + wsum[1]) + (wsum[2] + wsum[3]);
}

// ---------------- kernel 4: deterministic partial reduction ----------------
__global__ __launch_bounds__(256) void reduce_kernel(const float* __restrict__ partials,
                                                     float* __restrict__ out_loss) {
    const int tid = threadIdx.x;
    float s = 0.f;
#pragma unroll
    for (int u = 0; u < 16; ++u) s += partials[tid * 16 + u];
#pragma unroll
    for (int m = 1; m < 64; m <<= 1) s += __shfl_xor(s, m);
    __shared__ float wsum[4];
    if ((tid & 63) == 0) wsum[tid >> 6] = s;
    __syncthreads();
    if (tid == 0) *out_loss = 2.0f * ((wsum[0] + wsum[1]) + (wsum[2] + wsum[3]));
}

extern "C" void kernel_launch(void* const* d_in, const int* in_sizes, int n_in,
                              void* d_out, int out_size, void* d_ws, size_t ws_size,
                              hipStream_t stream) {
    const float* z  = (const float*)d_in[0];   // z_e       [65536,256]
    const float* cb = (const float*)d_in[1];   // codebook  [1024,256]
    float* out = (float*)d_out;                // [65536*256] z_q_out + [1] vq_loss
    char*  ws  = (char*)d_ws;

    int*   idx      = (int*)  (ws);                          // 65536 ints
    float* cn2      = (float*)(ws + N_TOKENS * 4);           // 1024 floats
    float* partials = (float*)(ws + N_TOKENS * 4 + N_EMB * 4); // 4096 floats

    cnorm_kernel <<<256, 256, 0, stream>>>(cb, cn2);
    argmin_kernel<<<N_TOKENS / BM, 256, 0, stream>>>(z, cb, cn2, idx);
    gather_kernel<<<(N_TOKENS * DIM / 4) / 1024, 256, 0, stream>>>(z, cb, idx, out, partials);
    reduce_kernel<<<1, 256, 0, stream>>>(partials, out + (size_t)N_TOKENS * DIM);
}

// Round 2
// 292.518 us; speedup vs baseline: 1.6710x; 1.6710x over previous
//
#include <hip/hip_runtime.h>
#include <float.h>

#define N_TOKENS 65536
#define N_EMB    1024
#define DIM      256

typedef __attribute__((ext_vector_type(8))) short bf16x8;
typedef __attribute__((ext_vector_type(4))) float f32x4;

__device__ __forceinline__ unsigned umin(unsigned a, unsigned b) { return a < b ? a : b; }
__device__ __forceinline__ unsigned umax(unsigned a, unsigned b) { return a > b ? a : b; }

__device__ __forceinline__ unsigned short bf16rne(float f) {
    unsigned u = __float_as_uint(f);
    unsigned r = (u + 0x7FFFu + ((u >> 16) & 1u)) >> 16;
    return (unsigned short)r;
}
__device__ __forceinline__ float bfh2f(unsigned short h) {
    return __uint_as_float(((unsigned)h) << 16);
}

// LDS fragment-order slot with XOR swizzle (2-way max bank aliasing on reads & writes)
__device__ __forceinline__ int slot16(int c, int hl, int s, int g) {
    return (((c * 2 + hl) * 8) + (s ^ ((c >> 2) & 7))) * 4 + (g ^ (c & 3));
}

// ---------------- kernel 1: codebook row squared-norms (UNCHANGED from round 1 — bitwise) ----
__global__ __launch_bounds__(256) void cnorm_kernel(const float* __restrict__ cb,
                                                    float* __restrict__ cn2) {
    int gwave = (blockIdx.x * 256 + threadIdx.x) >> 6;
    int lane  = threadIdx.x & 63;
    if (gwave >= N_EMB) return;
    float4 v = ((const float4*)cb)[gwave * 64 + lane];
    float s = v.x * v.x + v.y * v.y + v.z * v.z + v.w * v.w;
#pragma unroll
    for (int m = 1; m < 64; m <<= 1) s += __shfl_xor(s, m);
    if (lane == 0) cn2[gwave] = s;
}

// ---------------- kernel 2: codebook bf16 split (exact: cb = cbh + cbl up to dropped ll term) --
__global__ __launch_bounds__(256) void cbsplit_kernel(const float* __restrict__ cb,
                                                      unsigned short* __restrict__ cbh,
                                                      unsigned short* __restrict__ cbl) {
    int gid = blockIdx.x * 256 + threadIdx.x;        // 65536 threads, 4 elems each
    float4 v = ((const float4*)cb)[gid];
    float f[4] = {v.x, v.y, v.z, v.w};
    ushort4 h, l;
    unsigned short hu;
    hu = bf16rne(f[0]); h.x = hu; l.x = bf16rne(f[0] - bfh2f(hu));
    hu = bf16rne(f[1]); h.y = hu; l.y = bf16rne(f[1] - bfh2f(hu));
    hu = bf16rne(f[2]); h.z = hu; l.z = bf16rne(f[2] - bfh2f(hu));
    hu = bf16rne(f[3]); h.w = hu; l.w = bf16rne(f[3] - bfh2f(hu));
    ((ushort4*)cbh)[gid] = h;
    ((ushort4*)cbl)[gid] = l;
}

// ---------------- kernel 3: MFMA coarse pass -> top-4 candidate codes per token ---------------
// 512 blocks x 256 threads (4 waves). Wave owns 32 tokens; A (split bf16) in registers for all K.
// 32-code B-tiles double-buffered in LDS (fragment order + XOR swizzle), reg-prefetch staging.
__global__ __launch_bounds__(256, 2) void argmin4_kernel(
        const float* __restrict__ z, const unsigned short* __restrict__ cbh,
        const unsigned short* __restrict__ cbl, const float* __restrict__ cn2,
        ushort4* __restrict__ cand) {
    __shared__ unsigned short Bs[2][16384];          // 2 x 32KB
    const int t = threadIdx.x;
    const int lane = t & 63, w = t >> 6;
    const int col = lane & 15, g = lane >> 4;

    // ---- load & split A: 32 tokens/wave, full K=256 in registers (128 VGPRs) ----
    bf16x8 ah[2][8], al[2][8];
    const int rbase = blockIdx.x * 128 + w * 32 + col;
#pragma unroll
    for (int m = 0; m < 2; ++m) {
#pragma unroll
        for (int s = 0; s < 8; ++s) {
            const float* p = z + (size_t)(rbase + m * 16) * DIM + s * 32 + g * 8;
            float4 x0 = *(const float4*)p;
            float4 x1 = *(const float4*)(p + 4);
            float f[8] = {x0.x, x0.y, x0.z, x0.w, x1.x, x1.y, x1.z, x1.w};
            bf16x8 hv, lv;
#pragma unroll
            for (int j = 0; j < 8; ++j) {
                unsigned short hu = bf16rne(f[j]);
                hv[j] = (short)hu;
                lv[j] = (short)bf16rne(f[j] - bfh2f(hu));
            }
            ah[m][s] = hv;
            al[m][s] = lv;
        }
    }

    unsigned top4[2][4][4];
#pragma unroll
    for (int m = 0; m < 2; ++m)
#pragma unroll
        for (int r = 0; r < 4; ++r)
#pragma unroll
            for (int q = 0; q < 4; ++q) top4[m][r][q] = 0xFFFFFFFFu;

    uint4 st[8];
    auto stage_regs = [&](int T) {
#pragma unroll
        for (int i = 0; i < 8; ++i) {
            int hl = i >> 2;
            int chunk = (i & 3) * 256 + t;           // 0..1023
            int c = chunk >> 5, kc = chunk & 31;
            const unsigned short* src = (hl ? cbl : cbh) + (((size_t)(T * 32 + c)) << 8) + (kc << 3);
            st[i] = *(const uint4*)src;              // coalesced: 32 consecutive thr span a row
        }
    };
    auto write_lds = [&](int buf) {
#pragma unroll
        for (int i = 0; i < 8; ++i) {
            int hl = i >> 2;
            int chunk = (i & 3) * 256 + t;
            int c = chunk >> 5, kc = chunk & 31;
            int s = kc >> 2, gg = kc & 3;
            *(uint4*)&Bs[buf][slot16(c, hl, s, gg) * 8] = st[i];
        }
    };

    stage_regs(0);
    write_lds(0);
    __syncthreads();

    for (int T = 0; T < 32; ++T) {
        const int cur = T & 1;
        if (T < 31) stage_regs(T + 1);               // prefetch next tile (latency under MFMA)
        const f32x4 zero4 = {0.f, 0.f, 0.f, 0.f};
        f32x4 acc[2][2] = {{zero4, zero4}, {zero4, zero4}};
        const unsigned short* bs = Bs[cur];
#pragma unroll
        for (int s = 0; s < 8; ++s) {
            bf16x8 bh0 = *(const bf16x8*)&bs[slot16(col,      0, s, g) * 8];
            bf16x8 bl0 = *(const bf16x8*)&bs[slot16(col,      1, s, g) * 8];
            bf16x8 bh1 = *(const bf16x8*)&bs[slot16(col + 16, 0, s, g) * 8];
            bf16x8 bl1 = *(const bf16x8*)&bs[slot16(col + 16, 1, s, g) * 8];
#pragma unroll
            for (int m = 0; m < 2; ++m) {
                acc[m][0] = __builtin_amdgcn_mfma_f32_16x16x32_bf16(ah[m][s], bh0, acc[m][0], 0, 0, 0);
                acc[m][0] = __builtin_amdgcn_mfma_f32_16x16x32_bf16(al[m][s], bh0, acc[m][0], 0, 0, 0);
                acc[m][0] = __builtin_amdgcn_mfma_f32_16x16x32_bf16(ah[m][s], bl0, acc[m][0], 0, 0, 0);
                acc[m][1] = __builtin_amdgcn_mfma_f32_16x16x32_bf16(ah[m][s], bh1, acc[m][1], 0, 0, 0);
                acc[m][1] = __builtin_amdgcn_mfma_f32_16x16x32_bf16(al[m][s], bh1, acc[m][1], 0, 0, 0);
                acc[m][1] = __builtin_amdgcn_mfma_f32_16x16x32_bf16(ah[m][s], bl1, acc[m][1], 0, 0, 0);
            }
        }
        // scores: s = cn_k - 2*dot (no xn -> no 256-scale quantization); sortable key | code
#pragma unroll
        for (int nf = 0; nf < 2; ++nf) {
            int code = T * 32 + nf * 16 + col;
            float cn = cn2[code];
#pragma unroll
            for (int m = 0; m < 2; ++m)
#pragma unroll
                for (int r = 0; r < 4; ++r) {
                    float sc = fmaf(acc[m][nf][r], -2.0f, cn);
                    unsigned u = __float_as_uint(sc);
                    u ^= ((unsigned)(((int)u) >> 31)) | 0x80000000u;
                    unsigned key = (u & 0xFFFFFC00u) | (unsigned)code;
                    unsigned b0 = umax(top4[m][r][0], key); top4[m][r][0] = umin(top4[m][r][0], key);
                    unsigned b1 = umax(top4[m][r][1], b0);  top4[m][r][1] = umin(top4[m][r][1], b0);
                    unsigned b2 = umax(top4[m][r][2], b1);  top4[m][r][2] = umin(top4[m][r][2], b1);
                    top4[m][r][3] = umin(top4[m][r][3], b2);
                }
        }
        __syncthreads();                              // writes to buf^1 done by all; reads of cur done
        if (T < 31) write_lds(cur ^ 1);
        __syncthreads();
    }

    // ---- merge top-4 across the 16 col-lanes (bitonic merge of sorted quads) ----
#pragma unroll
    for (int m = 0; m < 2; ++m)
#pragma unroll
        for (int r = 0; r < 4; ++r) {
            unsigned k0 = top4[m][r][0], k1 = top4[m][r][1], k2 = top4[m][r][2], k3 = top4[m][r][3];
#pragma unroll
            for (int mask = 1; mask <= 8; mask <<= 1) {
                unsigned o0 = (unsigned)__shfl_xor((int)k0, mask);
                unsigned o1 = (unsigned)__shfl_xor((int)k1, mask);
                unsigned o2 = (unsigned)__shfl_xor((int)k2, mask);
                unsigned o3 = (unsigned)__shfl_xor((int)k3, mask);
                unsigned n0 = umin(k0, o3), n1 = umin(k1, o2), n2 = umin(k2, o1), n3 = umin(k3, o0);
                unsigned a = umin(n0, n2), c2 = umax(n0, n2);
                unsigned b = umin(n1, n3), d  = umax(n1, n3);
                k0 = umin(a, b); k1 = umax(a, b); k2 = umin(c2, d); k3 = umax(c2, d);
            }
            if (col == 0) {
                int token = blockIdx.x * 128 + w * 32 + m * 16 + g * 4 + r;
                ushort4 o;
                o.x = (unsigned short)(k0 & 1023u);
                o.y = (unsigned short)(k1 & 1023u);
                o.z = (unsigned short)(k2 & 1023u);
                o.w = (unsigned short)(k3 & 1023u);
                cand[token] = o;
            }
        }
}

// ---------------- kernel 4: exact fp32 rescore of top-4 (bit-identical to round-1 dist) -------
__global__ __launch_bounds__(64) void rescore_kernel(
        const float* __restrict__ z, const float* __restrict__ cb,
        const float* __restrict__ cn2, const ushort4* __restrict__ cand,
        int* __restrict__ out_idx) {
    __shared__ float Zs[64 * 256];                    // 64KB, XOR-swizzled banks
    const int lane = threadIdx.x;                     // block = 1 wave, 64 tokens
    const int t0 = blockIdx.x * 64;
    for (int it = 0; it < 256; ++it) {
        int e = it * 64 + lane;
        int r = e >> 8, c = e & 255;
        Zs[r * 256 + (c ^ (r & 31))] = z[(size_t)t0 * DIM + e];   // coalesced global read
    }
    __syncthreads();
    const int token = t0 + lane;
    const int sw = lane & 31;
    float xn = 0.f;
    for (int k = 0; k < 256; ++k) {                   // sequential fma: same order as round-1
        float a = Zs[lane * 256 + (k ^ sw)];
        xn = fmaf(a, a, xn);
    }
    ushort4 cd = cand[token];
    int cods[4] = {cd.x, cd.y, cd.z, cd.w};
    float bd = FLT_MAX;
    int bi = 0x7FFFFFFF;
    for (int j = 0; j < 4; ++j) {
        int c = cods[j];
        float dot = 0.f;
        for (int k = 0; k < 256; ++k) {               // sequential fma: same order as round-1
            float a = Zs[lane * 256 + (k ^ sw)];
            float b = cb[(size_t)c * DIM + k];
            dot = fmaf(a, b, dot);
        }
        float dist;
        {
#pragma clang fp contract(off)
            float t1 = xn + cn2[c];
            float t2 = 2.0f * dot;
            dist = t1 - t2;
        }
        if (dist < bd || (dist == bd && c < bi)) { bd = dist; bi = c; }
    }
    out_idx[token] = bi;
}

// ---------------- kernel 5: gather + straight-through out + loss partials (UNCHANGED) ---------
__global__ __launch_bounds__(256) void gather_kernel(
        const float* __restrict__ z, const float* __restrict__ cb,
        const int* __restrict__ idx, float* __restrict__ out,
        float* __restrict__ partials) {
    const int tid = threadIdx.x;
    const int f0  = blockIdx.x * 1024;
    float lsum = 0.f;
#pragma unroll
    for (int s = 0; s < 4; ++s) {
        int f     = f0 + s * 256 + tid;
        int token = f >> 6;
        int col   = f & 63;
        int k     = idx[token];
        float4 zv = ((const float4*)z)[f];
        float4 qv = ((const float4*)cb)[k * 64 + col];
        float4 ov;
        ov.x = zv.x + (qv.x - zv.x);
        ov.y = zv.y + (qv.y - zv.y);
        ov.z = zv.z + (qv.z - zv.z);
        ov.w = zv.w + (qv.w - zv.w);
        ((float4*)out)[f] = ov;
        float ex = zv.x - qv.x, ey = zv.y - qv.y, ez = zv.z - qv.z, ew = zv.w - qv.w;
        lsum += ex * ex + ey * ey + ez * ez + ew * ew;
    }
#pragma unroll
    for (int m = 1; m < 64; m <<= 1) lsum += __shfl_xor(lsum, m);
    __shared__ float wsum[4];
    if ((tid & 63) == 0) wsum[tid >> 6] = lsum;
    __syncthreads();
    if (tid == 0) partials[blockIdx.x] = (wsum[0] + wsum[1]) + (wsum[2] + wsum[3]);
}

// ---------------- kernel 6: deterministic partial reduction (UNCHANGED) -----------------------
__global__ __launch_bounds__(256) void reduce_kernel(const float* __restrict__ partials,
                                                     float* __restrict__ out_loss) {
    const int tid = threadIdx.x;
    float s = 0.f;
#pragma unroll
    for (int u = 0; u < 16; ++u) s += partials[tid * 16 + u];
#pragma unroll
    for (int m = 1; m < 64; m <<= 1) s += __shfl_xor(s, m);
    __shared__ float wsum[4];
    if ((tid & 63) == 0) wsum[tid >> 6] = s;
    __syncthreads();
    if (tid == 0) *out_loss = 2.0f * ((wsum[0] + wsum[1]) + (wsum[2] + wsum[3]));
}

extern "C" void kernel_launch(void* const* d_in, const int* in_sizes, int n_in,
                              void* d_out, int out_size, void* d_ws, size_t ws_size,
                              hipStream_t stream) {
    const float* z  = (const float*)d_in[0];   // z_e       [65536,256]
    const float* cb = (const float*)d_in[1];   // codebook  [1024,256]
    float* out = (float*)d_out;
    char*  ws  = (char*)d_ws;

    int*            idx      = (int*)(ws);                      // 256 KB
    ushort4*        cand     = (ushort4*)(ws + 262144);         // 512 KB
    float*          cn2      = (float*)(ws + 786432);           // 4 KB
    float*          partials = (float*)(ws + 790528);           // 16 KB
    unsigned short* cbh      = (unsigned short*)(ws + 806912);  // 512 KB
    unsigned short* cbl      = (unsigned short*)(ws + 1331200); // 512 KB

    cnorm_kernel  <<<256, 256, 0, stream>>>(cb, cn2);
    cbsplit_kernel<<<256, 256, 0, stream>>>(cb, cbh, cbl);
    argmin4_kernel<<<512, 256, 0, stream>>>(z, cbh, cbl, cn2, cand);
    rescore_kernel<<<1024, 64, 0, stream>>>(z, cb, cn2, cand, idx);
    gather_kernel <<<4096, 256, 0, stream>>>(z, cb, idx, out, partials);
    reduce_kernel <<<1, 256, 0, stream>>>(partials, out + (size_t)N_TOKENS * DIM);
}

// Round 3
// 190.548 us; speedup vs baseline: 2.5653x; 1.5351x over previous
//
#include <hip/hip_runtime.h>
#include <float.h>

#define N_TOKENS 65536
#define N_EMB    1024
#define DIM      256

typedef __attribute__((ext_vector_type(8))) short bf16x8;
typedef __attribute__((ext_vector_type(4))) float f32x4;

__device__ __forceinline__ unsigned umin(unsigned a, unsigned b) { return a < b ? a : b; }
__device__ __forceinline__ unsigned umax(unsigned a, unsigned b) { return a > b ? a : b; }

__device__ __forceinline__ unsigned short bf16rne(float f) {
    unsigned u = __float_as_uint(f);
    unsigned r = (u + 0x7FFFu + ((u >> 16) & 1u)) >> 16;
    return (unsigned short)r;
}

// LDS fragment-order slot with XOR swizzle (proven 0-conflict in round 2)
__device__ __forceinline__ int slot16(int c, int s, int g) {
    return ((c * 8) + (s ^ ((c >> 2) & 7))) * 4 + (g ^ (c & 3));
}

// ---------------- kernel 1: codebook row squared-norms (UNCHANGED) ----------------
__global__ __launch_bounds__(256) void cnorm_kernel(const float* __restrict__ cb,
                                                    float* __restrict__ cn2) {
    int gwave = (blockIdx.x * 256 + threadIdx.x) >> 6;
    int lane  = threadIdx.x & 63;
    if (gwave >= N_EMB) return;
    float4 v = ((const float4*)cb)[gwave * 64 + lane];
    float s = v.x * v.x + v.y * v.y + v.z * v.z + v.w * v.w;
#pragma unroll
    for (int m = 1; m < 64; m <<= 1) s += __shfl_xor(s, m);
    if (lane == 0) cn2[gwave] = s;
}

// ---------------- kernel 2: codebook -> bf16 (high part only) ----------------
__global__ __launch_bounds__(256) void cbconv_kernel(const float* __restrict__ cb,
                                                     unsigned short* __restrict__ cbh) {
    int gid = blockIdx.x * 256 + threadIdx.x;        // 65536 threads x float4
    float4 v = ((const float4*)cb)[gid];
    ushort4 h;
    h.x = bf16rne(v.x); h.y = bf16rne(v.y); h.z = bf16rne(v.z); h.w = bf16rne(v.w);
    ((ushort4*)cbh)[gid] = h;
}

// ---------------- kernel 3: single-bf16 MFMA coarse pass -> top-4 candidates ----------------
// 512 blocks x 256 thr (4 waves). Wave owns 32 tokens (A in regs, 64 VGPR).
// 32-code bf16 B-tiles (16 KB) double-buffered in LDS, reg-prefetch staging.
// Per-lane top-3 sorted keys, final 16-lane bitonic merge -> top-4.
__global__ __launch_bounds__(256, 3) void argmin4_kernel(
        const float* __restrict__ z, const unsigned short* __restrict__ cbh,
        const float* __restrict__ cn2, ushort4* __restrict__ cand) {
    __shared__ unsigned short Bs[2][8192];           // 2 x 16KB
    __shared__ float cnS[N_EMB];                     // 4KB
    const int t = threadIdx.x;
    const int lane = t & 63, w = t >> 6;
    const int col = lane & 15, g = lane >> 4;

#pragma unroll
    for (int i = 0; i < 4; ++i) cnS[t + i * 256] = cn2[t + i * 256];

    // ---- load A: 32 tokens/wave, full K=256, bf16 high only (64 VGPRs) ----
    bf16x8 ah[2][8];
    const int rbase = blockIdx.x * 128 + w * 32 + col;
#pragma unroll
    for (int m = 0; m < 2; ++m) {
#pragma unroll
        for (int s = 0; s < 8; ++s) {
            const float* p = z + (size_t)(rbase + m * 16) * DIM + s * 32 + g * 8;
            float4 x0 = *(const float4*)p;
            float4 x1 = *(const float4*)(p + 4);
            float f[8] = {x0.x, x0.y, x0.z, x0.w, x1.x, x1.y, x1.z, x1.w};
            bf16x8 hv;
#pragma unroll
            for (int j = 0; j < 8; ++j) hv[j] = (short)bf16rne(f[j]);
            ah[m][s] = hv;
        }
    }

    unsigned top3[2][4][3];
#pragma unroll
    for (int m = 0; m < 2; ++m)
#pragma unroll
        for (int r = 0; r < 4; ++r)
#pragma unroll
            for (int q = 0; q < 3; ++q) top3[m][r][q] = 0xFFFFFFFFu;

    // staging: 4 x uint4 per thread = one 16KB tile per block
    uint4 st[4];
    auto stage_regs = [&](int T) {
#pragma unroll
        for (int i = 0; i < 4; ++i) {
            int chunk = i * 256 + t;                 // 0..1023
            int c = chunk >> 5, kc = chunk & 31;
            st[i] = *(const uint4*)(cbh + (((size_t)(T * 32 + c)) << 8) + (kc << 3));
        }
    };
    auto write_lds = [&](int buf) {
#pragma unroll
        for (int i = 0; i < 4; ++i) {
            int chunk = i * 256 + t;
            int c = chunk >> 5, kc = chunk & 31;
            *(uint4*)&Bs[buf][slot16(c, kc >> 2, kc & 3) * 8] = st[i];
        }
    };

    stage_regs(0);
    write_lds(0);
    __syncthreads();

    for (int T = 0; T < 32; ++T) {
        const int cur = T & 1;
        if (T < 31) stage_regs(T + 1);               // prefetch hides under MFMA+epilogue
        const f32x4 zero4 = {0.f, 0.f, 0.f, 0.f};
        f32x4 acc[2][2] = {{zero4, zero4}, {zero4, zero4}};
        const unsigned short* bs = Bs[cur];
#pragma unroll
        for (int s = 0; s < 8; ++s) {
            bf16x8 bh0 = *(const bf16x8*)&bs[slot16(col,      s, g) * 8];
            bf16x8 bh1 = *(const bf16x8*)&bs[slot16(col + 16, s, g) * 8];
            acc[0][0] = __builtin_amdgcn_mfma_f32_16x16x32_bf16(ah[0][s], bh0, acc[0][0], 0, 0, 0);
            acc[0][1] = __builtin_amdgcn_mfma_f32_16x16x32_bf16(ah[0][s], bh1, acc[0][1], 0, 0, 0);
            acc[1][0] = __builtin_amdgcn_mfma_f32_16x16x32_bf16(ah[1][s], bh0, acc[1][0], 0, 0, 0);
            acc[1][1] = __builtin_amdgcn_mfma_f32_16x16x32_bf16(ah[1][s], bh1, acc[1][1], 0, 0, 0);
        }
        // ---- score + per-lane top-3 (keys: sign-folded fp32 bits, low 10 bits = code) ----
#pragma unroll
        for (int nf = 0; nf < 2; ++nf) {
            int code = T * 32 + nf * 16 + col;
            float cn = cnS[code];
#pragma unroll
            for (int m = 0; m < 2; ++m)
#pragma unroll
                for (int r = 0; r < 4; ++r) {
                    float sc = fmaf(acc[m][nf][r], -2.0f, cn);
                    unsigned u = __float_as_uint(sc);
                    u ^= ((unsigned)(((int)u) >> 31)) | 0x80000000u;
                    unsigned key = (u & 0xFFFFFC00u) | (unsigned)code;
                    unsigned b0 = umax(top3[m][r][0], key); top3[m][r][0] = umin(top3[m][r][0], key);
                    unsigned b1 = umax(top3[m][r][1], b0);  top3[m][r][1] = umin(top3[m][r][1], b0);
                    top3[m][r][2] = umin(top3[m][r][2], b1);
                }
        }
        __syncthreads();                              // all waves done reading cur
        if (T < 31) write_lds(cur ^ 1);
        __syncthreads();                              // next tile visible
    }

    // ---- merge per-lane sorted triples (+sentinel) across 16 col-lanes -> top-4 ----
#pragma unroll
    for (int m = 0; m < 2; ++m)
#pragma unroll
        for (int r = 0; r < 4; ++r) {
            unsigned k0 = top3[m][r][0], k1 = top3[m][r][1], k2 = top3[m][r][2], k3 = 0xFFFFFFFFu;
#pragma unroll
            for (int mask = 1; mask <= 8; mask <<= 1) {
                unsigned o0 = (unsigned)__shfl_xor((int)k0, mask);
                unsigned o1 = (unsigned)__shfl_xor((int)k1, mask);
                unsigned o2 = (unsigned)__shfl_xor((int)k2, mask);
                unsigned o3 = (unsigned)__shfl_xor((int)k3, mask);
                unsigned n0 = umin(k0, o3), n1 = umin(k1, o2), n2 = umin(k2, o1), n3 = umin(k3, o0);
                unsigned a = umin(n0, n2), c2 = umax(n0, n2);
                unsigned b = umin(n1, n3), d  = umax(n1, n3);
                k0 = umin(a, b); k1 = umax(a, b); k2 = umin(c2, d); k3 = umax(c2, d);
            }
            if (col == 0) {
                int token = blockIdx.x * 128 + w * 32 + m * 16 + g * 4 + r;
                ushort4 o;
                o.x = (unsigned short)(k0 & 1023u);
                o.y = (unsigned short)(k1 & 1023u);
                o.z = (unsigned short)(k2 & 1023u);
                o.w = (unsigned short)(k3 & 1023u);
                cand[token] = o;
            }
        }
}

// ---------------- kernel 4: exact fp32 rescore of top-4 (token per thread) ----------------
// argmin over cn_k - 2*dot_k (xn is token-uniform -> irrelevant to argmin).
// fp32 fma chains; accumulator stays at ~1e-2 scale so rounding noise ~1e-9 vs ~4e-3 gaps.
__global__ __launch_bounds__(256) void rescore_kernel(
        const float* __restrict__ z, const float* __restrict__ cb,
        const float* __restrict__ cn2, const ushort4* __restrict__ cand,
        int* __restrict__ out_idx) {
    const int token = blockIdx.x * 256 + threadIdx.x;
    ushort4 cd = cand[token];
    const float4* zr  = (const float4*)(z + (size_t)token * DIM);
    const float4* cp0 = (const float4*)(cb + (size_t)cd.x * DIM);
    const float4* cp1 = (const float4*)(cb + (size_t)cd.y * DIM);
    const float4* cp2 = (const float4*)(cb + (size_t)cd.z * DIM);
    const float4* cp3 = (const float4*)(cb + (size_t)cd.w * DIM);
    float d0 = 0.f, d1 = 0.f, d2 = 0.f, d3 = 0.f;
#pragma unroll 4
    for (int k = 0; k < 64; ++k) {
        float4 a  = zr[k];
        float4 b0 = cp0[k], b1 = cp1[k], b2 = cp2[k], b3 = cp3[k];
        d0 = fmaf(a.x, b0.x, d0); d0 = fmaf(a.y, b0.y, d0); d0 = fmaf(a.z, b0.z, d0); d0 = fmaf(a.w, b0.w, d0);
        d1 = fmaf(a.x, b1.x, d1); d1 = fmaf(a.y, b1.y, d1); d1 = fmaf(a.z, b1.z, d1); d1 = fmaf(a.w, b1.w, d1);
        d2 = fmaf(a.x, b2.x, d2); d2 = fmaf(a.y, b2.y, d2); d2 = fmaf(a.z, b2.z, d2); d2 = fmaf(a.w, b2.w, d2);
        d3 = fmaf(a.x, b3.x, d3); d3 = fmaf(a.y, b3.y, d3); d3 = fmaf(a.z, b3.z, d3); d3 = fmaf(a.w, b3.w, d3);
    }
    float s0 = fmaf(d0, -2.0f, cn2[cd.x]);
    float s1 = fmaf(d1, -2.0f, cn2[cd.y]);
    float s2 = fmaf(d2, -2.0f, cn2[cd.z]);
    float s3 = fmaf(d3, -2.0f, cn2[cd.w]);
    float bs = s0; int bi = cd.x;
    if (s1 < bs || (s1 == bs && (int)cd.y < bi)) { bs = s1; bi = cd.y; }
    if (s2 < bs || (s2 == bs && (int)cd.z < bi)) { bs = s2; bi = cd.z; }
    if (s3 < bs || (s3 == bs && (int)cd.w < bi)) { bs = s3; bi = cd.w; }
    out_idx[token] = bi;
}

// ---------------- kernel 5: gather + straight-through out + loss partials (UNCHANGED) ------
__global__ __launch_bounds__(256) void gather_kernel(
        const float* __restrict__ z, const float* __restrict__ cb,
        const int* __restrict__ idx, float* __restrict__ out,
        float* __restrict__ partials) {
    const int tid = threadIdx.x;
    const int f0  = blockIdx.x * 1024;
    float lsum = 0.f;
#pragma unroll
    for (int s = 0; s < 4; ++s) {
        int f     = f0 + s * 256 + tid;
        int token = f >> 6;
        int col   = f & 63;
        int k     = idx[token];
        float4 zv = ((const float4*)z)[f];
        float4 qv = ((const float4*)cb)[k * 64 + col];
        float4 ov;
        ov.x = zv.x + (qv.x - zv.x);
        ov.y = zv.y + (qv.y - zv.y);
        ov.z = zv.z + (qv.z - zv.z);
        ov.w = zv.w + (qv.w - zv.w);
        ((float4*)out)[f] = ov;
        float ex = zv.x - qv.x, ey = zv.y - qv.y, ez = zv.z - qv.z, ew = zv.w - qv.w;
        lsum += ex * ex + ey * ey + ez * ez + ew * ew;
    }
#pragma unroll
    for (int m = 1; m < 64; m <<= 1) lsum += __shfl_xor(lsum, m);
    __shared__ float wsum[4];
    if ((tid & 63) == 0) wsum[tid >> 6] = lsum;
    __syncthreads();
    if (tid == 0) partials[blockIdx.x] = (wsum[0] + wsum[1]) + (wsum[2] + wsum[3]);
}

// ---------------- kernel 6: deterministic partial reduction (UNCHANGED) --------------------
__global__ __launch_bounds__(256) void reduce_kernel(const float* __restrict__ partials,
                                                     float* __restrict__ out_loss) {
    const int tid = threadIdx.x;
    float s = 0.f;
#pragma unroll
    for (int u = 0; u < 16; ++u) s += partials[tid * 16 + u];
#pragma unroll
    for (int m = 1; m < 64; m <<= 1) s += __shfl_xor(s, m);
    __shared__ float wsum[4];
    if ((tid & 63) == 0) wsum[tid >> 6] = s;
    __syncthreads();
    if (tid == 0) *out_loss = 2.0f * ((wsum[0] + wsum[1]) + (wsum[2] + wsum[3]));
}

extern "C" void kernel_launch(void* const* d_in, const int* in_sizes, int n_in,
                              void* d_out, int out_size, void* d_ws, size_t ws_size,
                              hipStream_t stream) {
    const float* z  = (const float*)d_in[0];   // z_e       [65536,256]
    const float* cb = (const float*)d_in[1];   // codebook  [1024,256]
    float* out = (float*)d_out;
    char*  ws  = (char*)d_ws;

    int*            idx      = (int*)(ws);                      // 256 KB
    ushort4*        cand     = (ushort4*)(ws + 262144);         // 512 KB
    float*          cn2      = (float*)(ws + 786432);           // 4 KB
    float*          partials = (float*)(ws + 790528);           // 16 KB
    unsigned short* cbh      = (unsigned short*)(ws + 806912);  // 512 KB

    cnorm_kernel  <<<256, 256, 0, stream>>>(cb, cn2);
    cbconv_kernel <<<256, 256, 0, stream>>>(cb, cbh);
    argmin4_kernel<<<512, 256, 0, stream>>>(z, cbh, cn2, cand);
    rescore_kernel<<<256, 256, 0, stream>>>(z, cb, cn2, cand, idx);
    gather_kernel <<<4096, 256, 0, stream>>>(z, cb, idx, out, partials);
    reduce_kernel <<<1, 256, 0, stream>>>(partials, out + (size_t)N_TOKENS * DIM);
}

// Round 4
// 110.916 us; speedup vs baseline: 4.4070x; 1.7180x over previous
//
#include <hip/hip_runtime.h>
#include <float.h>
#include <stdint.h>

#define N_TOKENS 65536
#define N_EMB    1024
#define DIM      256

typedef __attribute__((ext_vector_type(8))) short bf16x8;
typedef __attribute__((ext_vector_type(4))) float f32x4;

__device__ __forceinline__ unsigned umin(unsigned a, unsigned b) { return a < b ? a : b; }
__device__ __forceinline__ unsigned umax(unsigned a, unsigned b) { return a > b ? a : b; }

__device__ __forceinline__ unsigned short bf16rne(float f) {
    unsigned u = __float_as_uint(f);
    unsigned r = (u + 0x7FFFu + ((u >> 16) & 1u)) >> 16;
    return (unsigned short)r;
}

// LDS fragment-order slot with XOR swizzle (proven 0-conflict in rounds 2-3)
__device__ __forceinline__ int slot16(int c, int s, int g) {
    return ((c * 8) + (s ^ ((c >> 2) & 7))) * 4 + (g ^ (c & 3));
}

// async global->LDS, 16B per lane (dest = wave-uniform base + lane*16)
__device__ __forceinline__ void gld_lds16(const void* g, void* l) {
    __builtin_amdgcn_global_load_lds(
        (__attribute__((address_space(1))) void*)(g),
        (__attribute__((address_space(3))) void*)(l), 16, 0, 0);
}

// ---------------- kernel 1: codebook row squared-norms (UNCHANGED) ----------------
__global__ __launch_bounds__(256) void cnorm_kernel(const float* __restrict__ cb,
                                                    float* __restrict__ cn2) {
    int gwave = (blockIdx.x * 256 + threadIdx.x) >> 6;
    int lane  = threadIdx.x & 63;
    if (gwave >= N_EMB) return;
    float4 v = ((const float4*)cb)[gwave * 64 + lane];
    float s = v.x * v.x + v.y * v.y + v.z * v.z + v.w * v.w;
#pragma unroll
    for (int m = 1; m < 64; m <<= 1) s += __shfl_xor(s, m);
    if (lane == 0) cn2[gwave] = s;
}

// ---------------- kernel 2: codebook -> bf16 pre-swizzled LDS image ----------------
// image granule gid (16B) = tile T=gid>>10, slot G=gid&1023. Inverse of slot16:
// c=G>>5; s=((G>>2)&7)^((c>>2)&7); g=(G&3)^(c&3); kc=s*4+g. Granule holds code
// (T*32+c), dims kc*8..+7 as bf16. argmin4 then stages tiles with linear
// global_load_lds and reads fragments with the round-3 slot16 addressing.
__global__ __launch_bounds__(256) void cbimg_kernel(const float* __restrict__ cb,
                                                    unsigned short* __restrict__ img) {
    int gid = blockIdx.x * 256 + threadIdx.x;     // 32768 granules
    int T = gid >> 10, G = gid & 1023;
    int c = G >> 5;
    int s = ((G >> 2) & 7) ^ ((c >> 2) & 7);
    int g = (G & 3) ^ (c & 3);
    int kc = (s << 2) | g;
    const float* p = cb + ((size_t)(T * 32 + c) << 8) + (kc << 3);
    float4 x0 = *(const float4*)p;
    float4 x1 = *(const float4*)(p + 4);
    float f[8] = {x0.x, x0.y, x0.z, x0.w, x1.x, x1.y, x1.z, x1.w};
    unsigned short h[8];
#pragma unroll
    for (int j = 0; j < 8; ++j) h[j] = bf16rne(f[j]);
    ((uint4*)img)[gid] = *(const uint4*)h;
}

// ---------------- kernel 3: MFMA coarse pass -> top-4 candidates ----------------
// 1024 blocks x 256 thr (4 waves), 16 tokens/wave, 4 blocks/CU (36KB LDS).
// B staged by global_load_lds from the pre-swizzled image: 1 barrier/tile,
// loads in flight across the whole compute phase (drained by __syncthreads).
__global__ __launch_bounds__(256, 4) void argmin4_kernel(
        const float* __restrict__ z, const unsigned short* __restrict__ cbimg,
        const float* __restrict__ cn2, ushort4* __restrict__ cand) {
    __shared__ unsigned short Bs[2][8192];        // 2 x 16KB
    __shared__ float cnS[N_EMB];                  // 4KB
    const int t = threadIdx.x;
    const int lane = t & 63, w = t >> 6;
    const int col = lane & 15, g = lane >> 4;

    // issue tile-0 stage (async; latency covered by A-load below)
    const char* srcL = (const char*)cbimg + w * 4096 + lane * 16;
    char* dstW[2] = {(char*)&Bs[0][0] + w * 4096, (char*)&Bs[1][0] + w * 4096};
#pragma unroll
    for (int j = 0; j < 4; ++j) gld_lds16(srcL + j * 1024, dstW[0] + j * 1024);

    // A: 16 tokens/wave, full K=256 bf16 in registers (32 VGPR)
    bf16x8 ah[8];
    const int row = blockIdx.x * 64 + w * 16 + col;
#pragma unroll
    for (int s = 0; s < 8; ++s) {
        const float* p = z + (size_t)row * DIM + s * 32 + g * 8;
        float4 x0 = *(const float4*)p;
        float4 x1 = *(const float4*)(p + 4);
        float f[8] = {x0.x, x0.y, x0.z, x0.w, x1.x, x1.y, x1.z, x1.w};
        bf16x8 hv;
#pragma unroll
        for (int j = 0; j < 8; ++j) hv[j] = (short)bf16rne(f[j]);
        ah[s] = hv;
    }
#pragma unroll
    for (int i = 0; i < 4; ++i) cnS[t + i * 256] = cn2[t + i * 256];

    unsigned top3[4][3];
#pragma unroll
    for (int r = 0; r < 4; ++r)
#pragma unroll
        for (int q = 0; q < 3; ++q) top3[r][q] = 0xFFFFFFFFu;

    __syncthreads();                              // drains tile-0 loads + barrier

    for (int T = 0; T < 32; ++T) {
        const int cur = T & 1;
        if (T < 31) {                             // async prefetch of next tile
            const char* s2 = srcL + (T + 1) * 16384;
#pragma unroll
            for (int j = 0; j < 4; ++j) gld_lds16(s2 + j * 1024, dstW[cur ^ 1] + j * 1024);
        }
        const f32x4 zero4 = {0.f, 0.f, 0.f, 0.f};
        f32x4 acc[2] = {zero4, zero4};
        const unsigned short* bs = Bs[cur];
#pragma unroll
        for (int s = 0; s < 8; ++s) {
            bf16x8 b0 = *(const bf16x8*)&bs[slot16(col,      s, g) * 8];
            bf16x8 b1 = *(const bf16x8*)&bs[slot16(col + 16, s, g) * 8];
            acc[0] = __builtin_amdgcn_mfma_f32_16x16x32_bf16(ah[s], b0, acc[0], 0, 0, 0);
            acc[1] = __builtin_amdgcn_mfma_f32_16x16x32_bf16(ah[s], b1, acc[1], 0, 0, 0);
        }
        // epilogue: 8 scores, identical key/top-3 logic to round 3
#pragma unroll
        for (int nf = 0; nf < 2; ++nf) {
            int code = T * 32 + nf * 16 + col;
            float cn = cnS[code];
#pragma unroll
            for (int r = 0; r < 4; ++r) {
                float sc = fmaf(acc[nf][r], -2.0f, cn);
                unsigned u = __float_as_uint(sc);
                u ^= ((unsigned)(((int)u) >> 31)) | 0x80000000u;
                unsigned key = (u & 0xFFFFFC00u) | (unsigned)code;
                unsigned b0 = umax(top3[r][0], key); top3[r][0] = umin(top3[r][0], key);
                unsigned b1 = umax(top3[r][1], b0);  top3[r][1] = umin(top3[r][1], b0);
                top3[r][2] = umin(top3[r][2], b1);
            }
        }
        __syncthreads();  // drain prefetch into cur^1; all waves done reading cur
    }

    // merge per-lane sorted triples (+sentinel) across 16 col-lanes -> top-4
#pragma unroll
    for (int r = 0; r < 4; ++r) {
        unsigned k0 = top3[r][0], k1 = top3[r][1], k2 = top3[r][2], k3 = 0xFFFFFFFFu;
#pragma unroll
        for (int mask = 1; mask <= 8; mask <<= 1) {
            unsigned o0 = (unsigned)__shfl_xor((int)k0, mask);
            unsigned o1 = (unsigned)__shfl_xor((int)k1, mask);
            unsigned o2 = (unsigned)__shfl_xor((int)k2, mask);
            unsigned o3 = (unsigned)__shfl_xor((int)k3, mask);
            unsigned n0 = umin(k0, o3), n1 = umin(k1, o2), n2 = umin(k2, o1), n3 = umin(k3, o0);
            unsigned a = umin(n0, n2), c2 = umax(n0, n2);
            unsigned b = umin(n1, n3), d  = umax(n1, n3);
            k0 = umin(a, b); k1 = umax(a, b); k2 = umin(c2, d); k3 = umax(c2, d);
        }
        if (col == 0) {
            int token = blockIdx.x * 64 + w * 16 + g * 4 + r;
            ushort4 o;
            o.x = (unsigned short)(k0 & 1023u);
            o.y = (unsigned short)(k1 & 1023u);
            o.z = (unsigned short)(k2 & 1023u);
            o.w = (unsigned short)(k3 & 1023u);
            cand[token] = o;
        }
    }
}

// ---------------- kernel 4: fused exact rescore + gather + loss ----------------
// 16 tokens/block. Phase 1: coalesced z load -> regs + LDS. Phase 2: 16 thr/token
// (4 codes x 4 dim-quarters) exact fp32 dots, lexicographic (score, code) min.
// Phase 3: straight-through output + loss partial, winner row coalesced from L2.
__global__ __launch_bounds__(256) void finalize_kernel(
        const float* __restrict__ z, const float* __restrict__ cb,
        const float* __restrict__ cn2, const ushort4* __restrict__ cand,
        float* __restrict__ out, float* __restrict__ partials) {
    __shared__ float zS[16 * 260];                // pad 4 floats/row
    __shared__ int   win[16];
    __shared__ float wsum[4];
    const int t  = threadIdx.x;
    const int f0 = blockIdx.x * 1024;             // float4 base, 16 tokens
    float4 zr[4];
#pragma unroll
    for (int s = 0; s < 4; ++s) {
        int f = s * 256 + t;
        zr[s] = ((const float4*)z)[f0 + f];
        int tl = f >> 6, col = f & 63;
        *(float4*)&zS[tl * 260 + col * 4] = zr[s];
    }
    __syncthreads();
    {
        const int tl = t >> 4;                    // local token
        const int token = blockIdx.x * 16 + tl;
        const int j = (t >> 2) & 3, q = t & 3;
        ushort4 cd = cand[token];
        int code = j == 0 ? cd.x : (j == 1 ? cd.y : (j == 2 ? cd.z : cd.w));
        const float4* cp = (const float4*)(cb + ((size_t)code << 8)) + q * 16;
        const float*  zp = &zS[tl * 260 + q * 64];
        float dot = 0.f;
#pragma unroll
        for (int i = 0; i < 16; ++i) {
            float4 b = cp[i];
            float4 a = *(const float4*)&zp[i * 4];
            dot = fmaf(a.x, b.x, dot); dot = fmaf(a.y, b.y, dot);
            dot = fmaf(a.z, b.z, dot); dot = fmaf(a.w, b.w, dot);
        }
        dot += __shfl_xor(dot, 1);
        dot += __shfl_xor(dot, 2);
        float sc = fmaf(dot, -2.0f, cn2[code]);
#pragma unroll
        for (int m = 4; m <= 8; m <<= 1) {        // min over the 4 codes
            float os = __shfl_xor(sc, m);
            int   oc = __shfl_xor(code, m);
            if (os < sc || (os == sc && oc < code)) { sc = os; code = oc; }
        }
        if ((t & 15) == 0) win[tl] = code;
    }
    __syncthreads();
    float lsum = 0.f;
#pragma unroll
    for (int s = 0; s < 4; ++s) {
        int f = s * 256 + t;
        int tl = f >> 6, col = f & 63;
        int k = win[tl];
        float4 qv = ((const float4*)cb)[k * 64 + col];
        float4 zv = zr[s];
        float4 ov;
        ov.x = zv.x + (qv.x - zv.x);
        ov.y = zv.y + (qv.y - zv.y);
        ov.z = zv.z + (qv.z - zv.z);
        ov.w = zv.w + (qv.w - zv.w);
        ((float4*)out)[f0 + f] = ov;
        float ex = zv.x - qv.x, ey = zv.y - qv.y, ez = zv.z - qv.z, ew = zv.w - qv.w;
        lsum += ex * ex + ey * ey + ez * ez + ew * ew;
    }
#pragma unroll
    for (int m = 1; m < 64; m <<= 1) lsum += __shfl_xor(lsum, m);
    if ((t & 63) == 0) wsum[t >> 6] = lsum;
    __syncthreads();
    if (t == 0) partials[blockIdx.x] = (wsum[0] + wsum[1]) + (wsum[2] + wsum[3]);
}

// ---------------- kernel 5: deterministic partial reduction (UNCHANGED) ----------------
__global__ __launch_bounds__(256) void reduce_kernel(const float* __restrict__ partials,
                                                     float* __restrict__ out_loss) {
    const int tid = threadIdx.x;
    float s = 0.f;
#pragma unroll
    for (int u = 0; u < 16; ++u) s += partials[tid * 16 + u];
#pragma unroll
    for (int m = 1; m < 64; m <<= 1) s += __shfl_xor(s, m);
    __shared__ float wsum[4];
    if ((tid & 63) == 0) wsum[tid >> 6] = s;
    __syncthreads();
    if (tid == 0) *out_loss = 2.0f * ((wsum[0] + wsum[1]) + (wsum[2] + wsum[3]));
}

extern "C" void kernel_launch(void* const* d_in, const int* in_sizes, int n_in,
                              void* d_out, int out_size, void* d_ws, size_t ws_size,
                              hipStream_t stream) {
    const float* z  = (const float*)d_in[0];   // z_e       [65536,256]
    const float* cb = (const float*)d_in[1];   // codebook  [1024,256]
    float* out = (float*)d_out;
    char*  ws  = (char*)d_ws;

    ushort4*        cand     = (ushort4*)(ws);                  // 512 KB
    float*          cn2      = (float*)(ws + 524288);           // 4 KB
    float*          partials = (float*)(ws + 528384);           // 16 KB
    unsigned short* cbimg    = (unsigned short*)(ws + 544768);  // 512 KB

    cnorm_kernel   <<<256, 256, 0, stream>>>(cb, cn2);
    cbimg_kernel   <<<128, 256, 0, stream>>>(cb, cbimg);
    argmin4_kernel <<<1024, 256, 0, stream>>>(z, cbimg, cn2, cand);
    finalize_kernel<<<4096, 256, 0, stream>>>(z, cb, cn2, cand, out, partials);
    reduce_kernel  <<<1, 256, 0, stream>>>(partials, out + (size_t)N_TOKENS * DIM);
}

// Round 5
// 66.199 us; speedup vs baseline: 7.3838x; 1.6755x over previous
//
#include <hip/hip_runtime.h>
#include <float.h>
#include <stdint.h>

#define N_TOKENS 65536
#define N_EMB    1024
#define DIM      256

typedef __attribute__((ext_vector_type(8))) short bf16x8;
typedef __attribute__((ext_vector_type(4))) float f32x4;

__device__ __forceinline__ unsigned short bf16rne(float f) {
    unsigned u = __float_as_uint(f);
    unsigned r = (u + 0x7FFFu + ((u >> 16) & 1u)) >> 16;
    return (unsigned short)r;
}

// LDS fragment-order slot with XOR swizzle (proven 0-conflict in rounds 2-4)
__device__ __forceinline__ int slot16(int c, int s, int g) {
    return ((c * 8) + (s ^ ((c >> 2) & 7))) * 4 + (g ^ (c & 3));
}

// async global->LDS, 16B per lane (dest = wave-uniform base + lane*16)
__device__ __forceinline__ void gld_lds16(const void* g, void* l) {
    __builtin_amdgcn_global_load_lds(
        (__attribute__((address_space(1))) void*)(g),
        (__attribute__((address_space(3))) void*)(l), 16, 0, 0);
}

// ---------------- kernel 1: codebook row squared-norms (UNCHANGED) ----------------
__global__ __launch_bounds__(256) void cnorm_kernel(const float* __restrict__ cb,
                                                    float* __restrict__ cn2) {
    int gwave = (blockIdx.x * 256 + threadIdx.x) >> 6;
    int lane  = threadIdx.x & 63;
    if (gwave >= N_EMB) return;
    float4 v = ((const float4*)cb)[gwave * 64 + lane];
    float s = v.x * v.x + v.y * v.y + v.z * v.z + v.w * v.w;
#pragma unroll
    for (int m = 1; m < 64; m <<= 1) s += __shfl_xor(s, m);
    if (lane == 0) cn2[gwave] = s;
}

// ---------------- kernel 2: codebook -> bf16 pre-swizzled LDS image (UNCHANGED) -------------
__global__ __launch_bounds__(256) void cbimg_kernel(const float* __restrict__ cb,
                                                    unsigned short* __restrict__ img) {
    int gid = blockIdx.x * 256 + threadIdx.x;     // 32768 granules
    int T = gid >> 10, G = gid & 1023;
    int c = G >> 5;
    int s = ((G >> 2) & 7) ^ ((c >> 2) & 7);
    int g = (G & 3) ^ (c & 3);
    int kc = (s << 2) | g;
    const float* p = cb + ((size_t)(T * 32 + c) << 8) + (kc << 3);
    float4 x0 = *(const float4*)p;
    float4 x1 = *(const float4*)(p + 4);
    float f[8] = {x0.x, x0.y, x0.z, x0.w, x1.x, x1.y, x1.z, x1.w};
    unsigned short h[8];
#pragma unroll
    for (int j = 0; j < 8; ++j) h[j] = bf16rne(f[j]);
    ((uint4*)img)[gid] = *(const uint4*)h;
}

// ---------------- kernel 3: fully fused VQ ----------------
// 512 blocks x 256 thr (4 waves), 32 tokens/wave. A = bf16(-2*z) in regs (64 VGPR),
// B tiles via global_load_lds double-buffer. Per-lane running argmin over
// score = cn + (-2x).c (fp32, no key quantization). 16-lane merge -> winner.
// Tail: out = codebook[winner] (coalesced), loss = sum(xn + score_win).
__global__ __launch_bounds__(256, 2) void fused_vq_kernel(
        const float* __restrict__ z, const unsigned short* __restrict__ cbimg,
        const float* __restrict__ cb, const float* __restrict__ cn2,
        float* __restrict__ out, float* __restrict__ partials) {
    __shared__ unsigned short Bs[2][8192];        // 2 x 16KB
    __shared__ float cnS[N_EMB];                  // 4KB
    __shared__ int   winS[128];
    __shared__ float distS[128];
    __shared__ float xnS[128];
    const int t = threadIdx.x;
    const int lane = t & 63, w = t >> 6;
    const int col = lane & 15, g = lane >> 4;

    // issue tile-0 stage (async; latency covered by A-load below)
    const char* srcL = (const char*)cbimg + w * 4096 + lane * 16;
    char* dstW[2] = {(char*)&Bs[0][0] + w * 4096, (char*)&Bs[1][0] + w * 4096};
#pragma unroll
    for (int j = 0; j < 4; ++j) gld_lds16(srcL + j * 1024, dstW[0] + j * 1024);

    // A: 32 tokens/wave, pre-scaled by -2 (exact in bf16); xn accumulated in fp32
    bf16x8 ah[2][8];
    float xnp[2] = {0.f, 0.f};
    const int rbase = blockIdx.x * 128 + w * 32 + col;
#pragma unroll
    for (int m = 0; m < 2; ++m) {
#pragma unroll
        for (int s = 0; s < 8; ++s) {
            const float* p = z + (size_t)(rbase + m * 16) * DIM + s * 32 + g * 8;
            float4 x0 = *(const float4*)p;
            float4 x1 = *(const float4*)(p + 4);
            float f[8] = {x0.x, x0.y, x0.z, x0.w, x1.x, x1.y, x1.z, x1.w};
            bf16x8 hv;
#pragma unroll
            for (int j = 0; j < 8; ++j) {
                xnp[m] = fmaf(f[j], f[j], xnp[m]);
                hv[j] = (short)bf16rne(-2.0f * f[j]);
            }
            ah[m][s] = hv;
        }
    }
    // complete xn over the 4 g-slices (tokens m*16+col)
#pragma unroll
    for (int m = 0; m < 2; ++m) {
        xnp[m] += __shfl_xor(xnp[m], 16);
        xnp[m] += __shfl_xor(xnp[m], 32);
        if (g == 0) xnS[w * 32 + m * 16 + col] = xnp[m];
    }
#pragma unroll
    for (int i = 0; i < 4; ++i) cnS[t + i * 256] = cn2[t + i * 256];

    float best[2][4];
    int   bidx[2][4];
#pragma unroll
    for (int m = 0; m < 2; ++m)
#pragma unroll
        for (int r = 0; r < 4; ++r) { best[m][r] = FLT_MAX; bidx[m][r] = 0; }

    __syncthreads();                              // drains tile-0 loads + barrier

#pragma unroll 2
    for (int T = 0; T < 32; ++T) {
        const int cur = T & 1;
        if (T < 31) {                             // async prefetch of next tile
            const char* s2 = srcL + (T + 1) * 16384;
#pragma unroll
            for (int j = 0; j < 4; ++j) gld_lds16(s2 + j * 1024, dstW[cur ^ 1] + j * 1024);
        }
        const f32x4 zero4 = {0.f, 0.f, 0.f, 0.f};
        f32x4 acc[2][2] = {{zero4, zero4}, {zero4, zero4}};
        const unsigned short* bs = Bs[cur];
#pragma unroll
        for (int s = 0; s < 8; ++s) {
            bf16x8 b0 = *(const bf16x8*)&bs[slot16(col,      s, g) * 8];
            bf16x8 b1 = *(const bf16x8*)&bs[slot16(col + 16, s, g) * 8];
            acc[0][0] = __builtin_amdgcn_mfma_f32_16x16x32_bf16(ah[0][s], b0, acc[0][0], 0, 0, 0);
            acc[0][1] = __builtin_amdgcn_mfma_f32_16x16x32_bf16(ah[0][s], b1, acc[0][1], 0, 0, 0);
            acc[1][0] = __builtin_amdgcn_mfma_f32_16x16x32_bf16(ah[1][s], b0, acc[1][0], 0, 0, 0);
            acc[1][1] = __builtin_amdgcn_mfma_f32_16x16x32_bf16(ah[1][s], b1, acc[1][1], 0, 0, 0);
        }
        // running per-lane argmin: score = acc + cn  (acc already holds -2*dot)
#pragma unroll
        for (int nf = 0; nf < 2; ++nf) {
            int code = T * 32 + nf * 16 + col;
            float cn = cnS[code];
#pragma unroll
            for (int m = 0; m < 2; ++m)
#pragma unroll
                for (int r = 0; r < 4; ++r) {
                    float sc = acc[m][nf][r] + cn;
                    if (sc < best[m][r]) { best[m][r] = sc; bidx[m][r] = code; }
                }
        }
        __syncthreads();  // drain prefetch into cur^1; all waves done reading cur
    }

    // merge across the 16 col-lanes; acc row r on lane = token m*16 + g*4 + r
#pragma unroll
    for (int m = 0; m < 2; ++m)
#pragma unroll
        for (int r = 0; r < 4; ++r) {
            float sc = best[m][r];
            int   cd = bidx[m][r];
#pragma unroll
            for (int mask = 1; mask <= 8; mask <<= 1) {
                float os = __shfl_xor(sc, mask);
                int   oc = __shfl_xor(cd, mask);
                if (os < sc || (os == sc && oc < cd)) { sc = os; cd = oc; }
            }
            if (col == 0) {
                int tl = w * 32 + m * 16 + g * 4 + r;
                winS[tl]  = cd;
                distS[tl] = sc;
            }
        }
    __syncthreads();

    // tail A: block loss partial = sum over 128 tokens of (xn + score_win)
    if (t < 64) {
        float s = (xnS[t] + distS[t]) + (xnS[t + 64] + distS[t + 64]);
#pragma unroll
        for (int m = 1; m < 64; m <<= 1) s += __shfl_xor(s, m);
        if (t == 0) partials[blockIdx.x] = s;
    }
    // tail B: output = codebook[winner] (wave reads one cb row / iter, coalesced)
    const size_t ob = (size_t)blockIdx.x * 8192;  // float4 units
#pragma unroll 4
    for (int i = 0; i < 32; ++i) {
        int f = i * 256 + t;
        int tl = f >> 6, c4 = f & 63;
        float4 q = ((const float4*)cb)[winS[tl] * 64 + c4];
        ((float4*)out)[ob + f] = q;
    }
}

// ---------------- kernel 4: deterministic partial reduction (512 partials) ----------------
__global__ __launch_bounds__(256) void reduce_kernel(const float* __restrict__ partials,
                                                     float* __restrict__ out_loss) {
    const int tid = threadIdx.x;
    float s = partials[tid] + partials[tid + 256];
#pragma unroll
    for (int m = 1; m < 64; m <<= 1) s += __shfl_xor(s, m);
    __shared__ float wsum[4];
    if ((tid & 63) == 0) wsum[tid >> 6] = s;
    __syncthreads();
    if (tid == 0) *out_loss = 2.0f * ((wsum[0] + wsum[1]) + (wsum[2] + wsum[3]));
}

extern "C" void kernel_launch(void* const* d_in, const int* in_sizes, int n_in,
                              void* d_out, int out_size, void* d_ws, size_t ws_size,
                              hipStream_t stream) {
    const float* z  = (const float*)d_in[0];   // z_e       [65536,256]
    const float* cb = (const float*)d_in[1];   // codebook  [1024,256]
    float* out = (float*)d_out;
    char*  ws  = (char*)d_ws;

    float*          cn2      = (float*)(ws);                    // 4 KB
    float*          partials = (float*)(ws + 4096);             // 2 KB
    unsigned short* cbimg    = (unsigned short*)(ws + 8192);    // 512 KB

    cnorm_kernel   <<<256, 256, 0, stream>>>(cb, cn2);
    cbimg_kernel   <<<128, 256, 0, stream>>>(cb, cbimg);
    fused_vq_kernel<<<512, 256, 0, stream>>>(z, cbimg, cb, cn2, out, partials);
    reduce_kernel  <<<1, 256, 0, stream>>>(partials, out + (size_t)N_TOKENS * DIM);
}

// Round 6
// 62.158 us; speedup vs baseline: 7.8639x; 1.0650x over previous
//
#include <hip/hip_runtime.h>
#include <float.h>
#include <stdint.h>

#define N_TOKENS 65536
#define N_EMB    1024
#define DIM      256

typedef __attribute__((ext_vector_type(8))) short bf16x8;
typedef __attribute__((ext_vector_type(4))) float f32x4;

__device__ __forceinline__ unsigned short bf16rne(float f) {
    unsigned u = __float_as_uint(f);
    unsigned r = (u + 0x7FFFu + ((u >> 16) & 1u)) >> 16;
    return (unsigned short)r;
}

// LDS fragment-order slot with XOR swizzle (proven 0-conflict in rounds 2-5)
__device__ __forceinline__ int slot16(int c, int s, int g) {
    return ((c * 8) + (s ^ ((c >> 2) & 7))) * 4 + (g ^ (c & 3));
}

// async global->LDS, 16B per lane (dest = wave-uniform base + lane*16)
__device__ __forceinline__ void gld_lds16(const void* g, void* l) {
    __builtin_amdgcn_global_load_lds(
        (__attribute__((address_space(1))) void*)(g),
        (__attribute__((address_space(3))) void*)(l), 16, 0, 0);
}

// ---------------- kernel 1: codebook row squared-norms (UNCHANGED) ----------------
__global__ __launch_bounds__(256) void cnorm_kernel(const float* __restrict__ cb,
                                                    float* __restrict__ cn2) {
    int gwave = (blockIdx.x * 256 + threadIdx.x) >> 6;
    int lane  = threadIdx.x & 63;
    if (gwave >= N_EMB) return;
    float4 v = ((const float4*)cb)[gwave * 64 + lane];
    float s = v.x * v.x + v.y * v.y + v.z * v.z + v.w * v.w;
#pragma unroll
    for (int m = 1; m < 64; m <<= 1) s += __shfl_xor(s, m);
    if (lane == 0) cn2[gwave] = s;
}

// ---------------- kernel 2: codebook -> bf16 pre-swizzled LDS image (UNCHANGED) -------------
__global__ __launch_bounds__(256) void cbimg_kernel(const float* __restrict__ cb,
                                                    unsigned short* __restrict__ img) {
    int gid = blockIdx.x * 256 + threadIdx.x;     // 32768 granules
    int T = gid >> 10, G = gid & 1023;
    int c = G >> 5;
    int s = ((G >> 2) & 7) ^ ((c >> 2) & 7);
    int g = (G & 3) ^ (c & 3);
    int kc = (s << 2) | g;
    const float* p = cb + ((size_t)(T * 32 + c) << 8) + (kc << 3);
    float4 x0 = *(const float4*)p;
    float4 x1 = *(const float4*)(p + 4);
    float f[8] = {x0.x, x0.y, x0.z, x0.w, x1.x, x1.y, x1.z, x1.w};
    unsigned short h[8];
#pragma unroll
    for (int j = 0; j < 8; ++j) h[j] = bf16rne(f[j]);
    ((uint4*)img)[gid] = *(const uint4*)h;
}

// ---------------- kernel 3: fully fused VQ, triple-buffered counted-vmcnt pipeline ----------
// 512 blocks x 256 thr (4 waves), 32 tokens/wave, A = bf16(-2*z) in regs.
// Per iter: s_waitcnt vmcnt(4) [tile T landed, T+1 in flight] -> s_barrier ->
// issue tile T+2 -> MFMA on tile T. No vmcnt(0) drain inside the loop.
__global__ __launch_bounds__(256, 2) void fused_vq_kernel(
        const float* __restrict__ z, const unsigned short* __restrict__ cbimg,
        const float* __restrict__ cb, const float* __restrict__ cn2,
        float* __restrict__ out, float* __restrict__ partials) {
    __shared__ unsigned short Bs[3][8192];        // 3 x 16KB
    __shared__ float cnS[N_EMB];                  // 4KB
    __shared__ int   winS[128];
    __shared__ float distS[128];
    __shared__ float xnS[128];
    const int t = threadIdx.x;
    const int lane = t & 63, w = t >> 6;
    const int col = lane & 15, g = lane >> 4;

    const char* srcL = (const char*)cbimg + w * 4096 + lane * 16;
    char* q0 = (char*)&Bs[0][0] + w * 4096;       // wave quarter of each buffer
    char* q1 = (char*)&Bs[1][0] + w * 4096;
    char* q2 = (char*)&Bs[2][0] + w * 4096;

    // prologue: issue tiles 0 and 1
#pragma unroll
    for (int j = 0; j < 4; ++j) gld_lds16(srcL + j * 1024, q0 + j * 1024);
#pragma unroll
    for (int j = 0; j < 4; ++j) gld_lds16(srcL + 16384 + j * 1024, q1 + j * 1024);

    // A: 32 tokens/wave, pre-scaled by -2 (exact in bf16); xn accumulated in fp32
    bf16x8 ah[2][8];
    float xnp[2] = {0.f, 0.f};
    const int rbase = blockIdx.x * 128 + w * 32 + col;
#pragma unroll
    for (int m = 0; m < 2; ++m) {
#pragma unroll
        for (int s = 0; s < 8; ++s) {
            const float* p = z + (size_t)(rbase + m * 16) * DIM + s * 32 + g * 8;
            float4 x0 = *(const float4*)p;
            float4 x1 = *(const float4*)(p + 4);
            float f[8] = {x0.x, x0.y, x0.z, x0.w, x1.x, x1.y, x1.z, x1.w};
            bf16x8 hv;
#pragma unroll
            for (int j = 0; j < 8; ++j) {
                xnp[m] = fmaf(f[j], f[j], xnp[m]);
                hv[j] = (short)bf16rne(-2.0f * f[j]);
            }
            ah[m][s] = hv;
        }
    }
#pragma unroll
    for (int m = 0; m < 2; ++m) {
        xnp[m] += __shfl_xor(xnp[m], 16);
        xnp[m] += __shfl_xor(xnp[m], 32);
        if (g == 0) xnS[w * 32 + m * 16 + col] = xnp[m];
    }
#pragma unroll
    for (int i = 0; i < 4; ++i) cnS[t + i * 256] = cn2[t + i * 256];

    float best[2][4];
    int   bidx[2][4];
#pragma unroll
    for (int m = 0; m < 2; ++m)
#pragma unroll
        for (int r = 0; r < 4; ++r) { best[m][r] = FLT_MAX; bidx[m][r] = 0; }

    // make cnS/xnS ds_writes visible before the first raw barrier
    asm volatile("s_waitcnt lgkmcnt(0)" ::: "memory");

    // rotating buffer pointers: read rd0 (tile T), write wq2 (tile T+2)
    const unsigned short* rd0 = &Bs[0][0];
    const unsigned short* rd1 = &Bs[1][0];
    const unsigned short* rd2 = &Bs[2][0];
    char *wq0 = q0, *wq1 = q1, *wq2 = q2;

    for (int T = 0; T < 32; ++T) {
        if (T < 31) asm volatile("s_waitcnt vmcnt(4)" ::: "memory");
        else        asm volatile("s_waitcnt vmcnt(0)" ::: "memory");
        __builtin_amdgcn_s_barrier();             // all waves: tile T resident
        __builtin_amdgcn_sched_barrier(0);
        if (T + 2 < 32) {                         // issue tile T+2 (buffer read at T-1)
            const char* s2 = srcL + (T + 2) * 16384;
#pragma unroll
            for (int j = 0; j < 4; ++j) gld_lds16(s2 + j * 1024, wq2 + j * 1024);
        }
        const f32x4 zero4 = {0.f, 0.f, 0.f, 0.f};
        f32x4 acc[2][2] = {{zero4, zero4}, {zero4, zero4}};
        const unsigned short* bs = rd0;
        __builtin_amdgcn_s_setprio(1);
#pragma unroll
        for (int s = 0; s < 8; ++s) {
            bf16x8 b0 = *(const bf16x8*)&bs[slot16(col,      s, g) * 8];
            bf16x8 b1 = *(const bf16x8*)&bs[slot16(col + 16, s, g) * 8];
            acc[0][0] = __builtin_amdgcn_mfma_f32_16x16x32_bf16(ah[0][s], b0, acc[0][0], 0, 0, 0);
            acc[0][1] = __builtin_amdgcn_mfma_f32_16x16x32_bf16(ah[0][s], b1, acc[0][1], 0, 0, 0);
            acc[1][0] = __builtin_amdgcn_mfma_f32_16x16x32_bf16(ah[1][s], b0, acc[1][0], 0, 0, 0);
            acc[1][1] = __builtin_amdgcn_mfma_f32_16x16x32_bf16(ah[1][s], b1, acc[1][1], 0, 0, 0);
        }
        __builtin_amdgcn_s_setprio(0);
        // running per-lane argmin: score = acc + cn  (acc already holds -2*dot)
#pragma unroll
        for (int nf = 0; nf < 2; ++nf) {
            int code = T * 32 + nf * 16 + col;
            float cn = cnS[code];
#pragma unroll
            for (int m = 0; m < 2; ++m)
#pragma unroll
                for (int r = 0; r < 4; ++r) {
                    float sc = acc[m][nf][r] + cn;
                    if (sc < best[m][r]) { best[m][r] = sc; bidx[m][r] = code; }
                }
        }
        // rotate buffers
        const unsigned short* tr = rd0; rd0 = rd1; rd1 = rd2; rd2 = tr;
        char* tw = wq0; wq0 = wq1; wq1 = wq2; wq2 = tw;
    }

    // merge across the 16 col-lanes; acc row r on lane = token m*16 + g*4 + r
#pragma unroll
    for (int m = 0; m < 2; ++m)
#pragma unroll
        for (int r = 0; r < 4; ++r) {
            float sc = best[m][r];
            int   cd = bidx[m][r];
#pragma unroll
            for (int mask = 1; mask <= 8; mask <<= 1) {
                float os = __shfl_xor(sc, mask);
                int   oc = __shfl_xor(cd, mask);
                if (os < sc || (os == sc && oc < cd)) { sc = os; cd = oc; }
            }
            if (col == 0) {
                int tl = w * 32 + m * 16 + g * 4 + r;
                winS[tl]  = cd;
                distS[tl] = sc;
            }
        }
    __syncthreads();

    // tail A: block loss partial = sum over 128 tokens of (xn + score_win)
    if (t < 64) {
        float s = (xnS[t] + distS[t]) + (xnS[t + 64] + distS[t + 64]);
#pragma unroll
        for (int m = 1; m < 64; m <<= 1) s += __shfl_xor(s, m);
        if (t == 0) partials[blockIdx.x] = s;
    }
    // tail B: output = codebook[winner] (wave reads one cb row / iter, coalesced)
    const size_t ob = (size_t)blockIdx.x * 8192;  // float4 units
#pragma unroll 4
    for (int i = 0; i < 32; ++i) {
        int f = i * 256 + t;
        int tl = f >> 6, c4 = f & 63;
        float4 q = ((const float4*)cb)[winS[tl] * 64 + c4];
        ((float4*)out)[ob + f] = q;
    }
}

// ---------------- kernel 4: deterministic partial reduction (512 partials) ----------------
__global__ __launch_bounds__(256) void reduce_kernel(const float* __restrict__ partials,
                                                     float* __restrict__ out_loss) {
    const int tid = threadIdx.x;
    float s = partials[tid] + partials[tid + 256];
#pragma unroll
    for (int m = 1; m < 64; m <<= 1) s += __shfl_xor(s, m);
    __shared__ float wsum[4];
    if ((tid & 63) == 0) wsum[tid >> 6] = s;
    __syncthreads();
    if (tid == 0) *out_loss = 2.0f * ((wsum[0] + wsum[1]) + (wsum[2] + wsum[3]));
}

extern "C" void kernel_launch(void* const* d_in, const int* in_sizes, int n_in,
                              void* d_out, int out_size, void* d_ws, size_t ws_size,
                              hipStream_t stream) {
    const float* z  = (const float*)d_in[0];   // z_e       [65536,256]
    const float* cb = (const float*)d_in[1];   // codebook  [1024,256]
    float* out = (float*)d_out;
    char*  ws  = (char*)d_ws;

    float*          cn2      = (float*)(ws);                    // 4 KB
    float*          partials = (float*)(ws + 4096);             // 2 KB
    unsigned short* cbimg    = (unsigned short*)(ws + 8192);    // 512 KB

    cnorm_kernel   <<<256, 256, 0, stream>>>(cb, cn2);
    cbimg_kernel   <<<128, 256, 0, stream>>>(cb, cbimg);
    fused_vq_kernel<<<512, 256, 0, stream>>>(z, cbimg, cb, cn2, out, partials);
    reduce_kernel  <<<1, 256, 0, stream>>>(partials, out + (size_t)N_TOKENS * DIM);
}